// Round 1
// baseline (6897.712 us; speedup 1.0000x reference)
//
#include <hip/hip_runtime.h>

#define T_STEPS 256
#define HH      100
#define G4      400   // 4*H
#define ROWS    8     // batch rows per block

// ---------------- pack kernel ----------------
// ws float layout:
//   [0      .. 40000)  P1 = W_hh1 packed: P[kq][j][kk] = W[j][4*kq+kk]   (kq<25, j<400, kk<4)
//   [40000  .. 80000)  P2 = W_ih2 packed
//   [80000  ..120000)  P3 = W_hh2 packed
//   [120000 ..120400)  bias1 = b_ih1 + b_hh1
//   [120400 ..120800)  bias2 = b_ih2 + b_hh2
//   [120800 ..121200)  wi1   = W_ih1[:,0]
//   [121200 ..121300)  wlin  = W_lin[0][:]
//   [121300]           blin
#define WS_TOTAL 121301

__global__ __launch_bounds__(256) void pack_kernel(
    const float* __restrict__ Whh1, const float* __restrict__ Wih2,
    const float* __restrict__ Whh2,
    const float* __restrict__ bih1, const float* __restrict__ bhh1,
    const float* __restrict__ bih2, const float* __restrict__ bhh2,
    const float* __restrict__ Wih1, const float* __restrict__ Wlin,
    const float* __restrict__ blin, float* __restrict__ ws) {
  int idx = blockIdx.x * 256 + threadIdx.x;
  if (idx < 120000) {
    int m   = idx / 40000;
    int rem = idx - m * 40000;         // (kq*400 + j)*4 + kk
    int kk  = rem & 3;
    int t2  = rem >> 2;                // kq*400 + j
    int kq  = t2 / 400;
    int j   = t2 - kq * 400;
    const float* W = (m == 0) ? Whh1 : (m == 1) ? Wih2 : Whh2;
    ws[idx] = W[j * HH + kq * 4 + kk];
  } else if (idx < 120400) {
    int j = idx - 120000; ws[idx] = bih1[j] + bhh1[j];
  } else if (idx < 120800) {
    int j = idx - 120400; ws[idx] = bih2[j] + bhh2[j];
  } else if (idx < 121200) {
    ws[idx] = Wih1[idx - 120800];
  } else if (idx < 121300) {
    ws[idx] = Wlin[idx - 121200];
  } else if (idx == 121300) {
    ws[idx] = blin[0];
  }
}

// ---------------- device helpers ----------------
__device__ __forceinline__ float sigf(float v) {
  return 1.0f / (1.0f + __expf(-v));
}
__device__ __forceinline__ float tanh_fast(float v) {
  // 1 - 2/(e^{2v}+1); saturates correctly at +/-1 for |v| large
  float t = __expf(2.0f * v);
  return 1.0f - 2.0f / (t + 1.0f);
}

// one packed matrix (P, 25*1600 floats) times h-block (hb[rows][HH]) into acc
__device__ __forceinline__ void mv_acc(const float* __restrict__ P,
                                       const float (*__restrict__ hb)[HH],
                                       int rg, int col, bool x4, int j3,
                                       float a0[4], float a1[4], float a2[4],
                                       float a3[4]) {
#pragma unroll 5
  for (int kq = 0; kq < 25; ++kq) {
    float4 hq[4];
#pragma unroll
    for (int r = 0; r < 4; ++r)
      hq[r] = *(const float4*)&hb[rg + r][kq * 4];
    const float* pb = P + kq * 1600;
    float4 w0 = *(const float4*)&pb[col * 4];
    float4 w1 = *(const float4*)&pb[col * 4 + 512];
    float4 w2 = *(const float4*)&pb[col * 4 + 1024];
#pragma unroll
    for (int r = 0; r < 4; ++r) {
      a0[r] += w0.x * hq[r].x + w0.y * hq[r].y + w0.z * hq[r].z + w0.w * hq[r].w;
      a1[r] += w1.x * hq[r].x + w1.y * hq[r].y + w1.z * hq[r].z + w1.w * hq[r].w;
      a2[r] += w2.x * hq[r].x + w2.y * hq[r].y + w2.z * hq[r].z + w2.w * hq[r].w;
    }
    if (x4) {
      float4 w3 = *(const float4*)&pb[j3 * 4];
#pragma unroll
      for (int r = 0; r < 4; ++r)
        a3[r] += w3.x * hq[r].x + w3.y * hq[r].y + w3.z * hq[r].z + w3.w * hq[r].w;
    }
  }
}

// ---------------- main persistent kernel ----------------
__global__ __launch_bounds__(256) void lstm_persist(
    const float* __restrict__ x, const float* __restrict__ ws,
    float* __restrict__ out, int T) {
  const float* P1    = ws;
  const float* P2    = ws + 40000;
  const float* P3    = ws + 80000;
  const float* bias1 = ws + 120000;
  const float* bias2 = ws + 120400;
  const float* wi1   = ws + 120800;
  const float* wlin  = ws + 121200;

  __shared__ float h1[ROWS][HH];
  __shared__ float h2[ROWS][HH];
  __shared__ float gb[ROWS][G4];
  __shared__ float xs[ROWS];

  const int tid = threadIdx.x;
  const int r0  = blockIdx.x * ROWS;

  for (int i = tid; i < ROWS * HH; i += 256) {
    (&h1[0][0])[i] = 0.0f;
    (&h2[0][0])[i] = 0.0f;
  }
  float c1c[4] = {0.f, 0.f, 0.f, 0.f};
  float c2c[4] = {0.f, 0.f, 0.f, 0.f};
  if (tid < ROWS) xs[tid] = x[(r0 + tid) * T];
  __syncthreads();

  const int  col = tid & 127;
  const int  rg  = (tid >> 7) * 4;   // rows rg..rg+3
  const bool x4  = (col < 16);
  const int  j3  = col + 384;

  // hoisted loop-invariant scalars
  const float b1_0 = bias1[col], b1_1 = bias1[col + 128], b1_2 = bias1[col + 256];
  const float b1_3 = x4 ? bias1[j3] : 0.0f;
  const float wx0  = wi1[col],  wx1  = wi1[col + 128],  wx2  = wi1[col + 256];
  const float wx3  = x4 ? wi1[j3] : 0.0f;
  const float b2_0 = bias2[col], b2_1 = bias2[col + 128], b2_2 = bias2[col + 256];
  const float b2_3 = x4 ? bias2[j3] : 0.0f;

#pragma unroll 1
  for (int t = 0; t < T; ++t) {
    // ======== layer-1 gate matvec ========
    float a0[4], a1[4], a2[4], a3[4];
#pragma unroll
    for (int r = 0; r < 4; ++r) {
      float xv = xs[rg + r];
      a0[r] = b1_0 + wx0 * xv;
      a1[r] = b1_1 + wx1 * xv;
      a2[r] = b1_2 + wx2 * xv;
      a3[r] = b1_3 + wx3 * xv;
    }
    mv_acc(P1, (const float(*)[HH])h1, rg, col, x4, j3, a0, a1, a2, a3);
#pragma unroll
    for (int r = 0; r < 4; ++r) {
      gb[rg + r][col]       = a0[r];
      gb[rg + r][col + 128] = a1[r];
      gb[rg + r][col + 256] = a2[r];
      if (x4) gb[rg + r][j3] = a3[r];
    }
    __syncthreads();

    // ======== layer-1 activations ========
#pragma unroll
    for (int u = 0; u < 4; ++u) {
      int idx = tid + 256 * u;
      if (idx < ROWS * HH) {
        int r = idx / HH;
        int n = idx - r * HH;
        float gi = gb[r][n], gf = gb[r][n + 100], gg = gb[r][n + 200], go = gb[r][n + 300];
        float iv = sigf(gi), fv = sigf(gf), gv = tanh_fast(gg), ov = sigf(go);
        float c  = fv * c1c[u] + iv * gv;
        c1c[u]   = c;
        h1[r][n] = ov * tanh_fast(c);
      }
    }
    __syncthreads();

    // ======== layer-2 gate matvec (W_ih2@h1 + W_hh2@h2) ========
#pragma unroll
    for (int r = 0; r < 4; ++r) {
      a0[r] = b2_0; a1[r] = b2_1; a2[r] = b2_2; a3[r] = b2_3;
    }
    mv_acc(P2, (const float(*)[HH])h1, rg, col, x4, j3, a0, a1, a2, a3);
    mv_acc(P3, (const float(*)[HH])h2, rg, col, x4, j3, a0, a1, a2, a3);
#pragma unroll
    for (int r = 0; r < 4; ++r) {
      gb[rg + r][col]       = a0[r];
      gb[rg + r][col + 128] = a1[r];
      gb[rg + r][col + 256] = a2[r];
      if (x4) gb[rg + r][j3] = a3[r];
    }
    __syncthreads();

    // ======== layer-2 activations (+ prefetch next x) ========
#pragma unroll
    for (int u = 0; u < 4; ++u) {
      int idx = tid + 256 * u;
      if (idx < ROWS * HH) {
        int r = idx / HH;
        int n = idx - r * HH;
        float gi = gb[r][n], gf = gb[r][n + 100], gg = gb[r][n + 200], go = gb[r][n + 300];
        float iv = sigf(gi), fv = sigf(gf), gv = tanh_fast(gg), ov = sigf(go);
        float c  = fv * c2c[u] + iv * gv;
        c2c[u]   = c;
        h2[r][n] = ov * tanh_fast(c);
      }
    }
    if (tid < ROWS && (t + 1) < T) xs[tid] = x[(r0 + tid) * T + t + 1];
    __syncthreads();
  }

  // ======== output: out[r] = h2[r]·wlin + blin ========
  {
    int rr = tid >> 5;   // 0..7
    int lk = tid & 31;
    float p = 0.0f;
#pragma unroll
    for (int n0 = 0; n0 < 4; ++n0) {
      int n = lk + 32 * n0;
      if (n < HH) p += h2[rr][n] * wlin[n];
    }
#pragma unroll
    for (int s = 16; s > 0; s >>= 1) p += __shfl_down(p, s, 32);
    if (lk == 0) out[r0 + rr] = p + ws[121300];
  }
}

// ---------------- launcher ----------------
extern "C" void kernel_launch(void* const* d_in, const int* in_sizes, int n_in,
                              void* d_out, int out_size, void* d_ws, size_t ws_size,
                              hipStream_t stream) {
  const float* x    = (const float*)d_in[0];
  const float* Wih1 = (const float*)d_in[1];
  const float* Whh1 = (const float*)d_in[2];
  const float* bih1 = (const float*)d_in[3];
  const float* bhh1 = (const float*)d_in[4];
  const float* Wih2 = (const float*)d_in[5];
  const float* Whh2 = (const float*)d_in[6];
  const float* bih2 = (const float*)d_in[7];
  const float* bhh2 = (const float*)d_in[8];
  const float* Wlin = (const float*)d_in[9];
  const float* blin = (const float*)d_in[10];

  float* ws  = (float*)d_ws;
  float* out = (float*)d_out;

  const int B = in_sizes[0] / T_STEPS;   // 2048

  pack_kernel<<<(WS_TOTAL + 255) / 256, 256, 0, stream>>>(
      Whh1, Wih2, Whh2, bih1, bhh1, bih2, bhh2, Wih1, Wlin, blin, ws);

  lstm_persist<<<B / ROWS, 256, 0, stream>>>(x, ws, out, T_STEPS);
}